// Round 5
// baseline (170.324 us; speedup 1.0000x reference)
//
#include <hip/hip_runtime.h>

typedef _Float16 f16;
typedef f16 f16x8 __attribute__((ext_vector_type(8)));
typedef f16 f16x4 __attribute__((ext_vector_type(4)));
typedef float f32x4 __attribute__((ext_vector_type(4)));

// ---- LDS tile strides/offsets (units: f16 elements) ----
// x0: 19 rows x 24 cols (gx in [tx*16-4,  tx*16+20)), stride 28
// x1: 36 rows x 44 cols (gx in [tx*32-4,  tx*32+40)), stride 48
// x2: 76 rows x 88 cols (gx in [tx*64-8,  tx*64+80)), stride 92
#define S0 28
#define S1 48
#define S2 92
#define T0OFF 0
#define T1OFF (19 * S0)                 // 532
#define T2OFF (T1OFF + 36 * S1)         // 2260
#define TILEH (T2OFF + 76 * S2)         // 9252 f16 = 18504 B
#define SCRSTR 68                       // scratch row stride (floats)
#define SMEM_BYTES 18560                // max(tiles 18504 B, scratch 17408 B), 16B-aligned
#define LOG2E 1.4426950408889634f

// K' = 256 layout (8 ksteps of 32):
//  kp in [0,16)   : layer0, ki=kp>>2, kj=kp&3   ; real iff ki<3 && kj<3 -> orig = 3*ki+kj
//  kp in [16,64)  : layer1, kk=kp-16, ki=kk>>3, kj=kk&7 ; real iff kj<6 -> orig = 9+6*ki+kj
//  kp in [64,256) : layer2, kk=kp-64, ki=kk>>4, kj=kk&15; real iff kj<12 -> orig = 45+12*ki+kj
__global__ void prep_wt(const float* __restrict__ W, f16* __restrict__ Wt) {
  const int n  = blockIdx.x;    // 0..63
  const int kp = threadIdx.x;   // 0..255
  int orig = -1;
  if (kp < 16)      { int ki = kp >> 2, kj = kp & 3;                  if (ki < 3 && kj < 3) orig = 3*ki + kj; }
  else if (kp < 64) { int kk = kp - 16; int ki = kk >> 3, kj = kk & 7; if (kj < 6)          orig = 9 + 6*ki + kj; }
  else              { int kk = kp - 64; int ki = kk >> 4, kj = kk & 15; if (kj < 12)        orig = 45 + 12*ki + kj; }
  float v = (orig >= 0) ? W[orig * 64 + n] : 0.f;
  Wt[n * 256 + kp] = (f16)v;
}

__global__ __launch_bounds__(256, 5) void fuse_kernel(
    const float* __restrict__ x0, const float* __restrict__ x1,
    const float* __restrict__ x2, const f16* __restrict__ Wt,
    float* __restrict__ out)
{
  // scratch aliases tiles: tiles used staging+K-loop, scratch used in epilogue
  // (separated by a __syncthreads after the K-loop).
  __shared__ __align__(16) char smem_raw[SMEM_BYTES];
  f16*   tiles   = (f16*)smem_raw;
  float* scratch = (float*)smem_raw;

  const int tid  = threadIdx.x;
  const int bid  = blockIdx.x;
  // XCD-locality swizzle: all 16 tiles of one image share bid&7 (same XCD
  // under round-robin dispatch) -> halo re-fetches hit that XCD's L2.
  const int nb   = ((bid >> 7) << 3) | (bid & 7);   // image 0..63
  const int tl   = (bid >> 3) & 15;                 // tile 0..15
  const int ty   = tl >> 2;
  const int tx   = tl & 3;
  const int lane = tid & 63;
  const int wid  = tid >> 6;
  const int ln   = lane & 15;
  const int quad = lane >> 4;

  // ================= issue x2 loads FIRST (biggest input, longest latency) ==
  // 76 rows x 22 float4 = 1672 items
  f32x4 v2[7];
  int   off2[7];
  bool  ok2[7];
  {
    const float* img = x2 + nb * 65536;
    #pragma unroll
    for (int i = 0; i < 7; ++i) {
      int idx = tid + 256 * i;
      int r  = idx / 22, c4 = idx - r * 22;
      int gy = ty * 64 - 4 + r;
      int gx = tx * 64 - 8 + 4 * c4;
      bool inb = (idx < 1672) && ((unsigned)gy < 256u) && ((unsigned)gx < 256u);
      v2[i]  = inb ? *(const f32x4*)(img + gy * 256 + gx) : (f32x4){0.f, 0.f, 0.f, 0.f};
      off2[i] = T2OFF + r * S2 + 4 * c4;
      ok2[i]  = (idx < 1672);
    }
  }

  // ================= stage x1 (36 x 11 float4 = 396) and x0 (19 x 6 = 114) ==
  {
    const float* img = x1 + nb * 16384;
    #pragma unroll
    for (int i = 0; i < 2; ++i) {
      int idx = tid + 256 * i;
      int r  = idx / 11, c4 = idx - r * 11;
      int gy = ty * 32 - 2 + r;
      int gx = tx * 32 - 4 + 4 * c4;
      bool inb = (idx < 396) && ((unsigned)gy < 128u) && ((unsigned)gx < 128u);
      f32x4 t = inb ? *(const f32x4*)(img + gy * 128 + gx) : (f32x4){0.f, 0.f, 0.f, 0.f};
      if (idx < 396) {
        f16x4 h; h[0] = (f16)t[0]; h[1] = (f16)t[1]; h[2] = (f16)t[2]; h[3] = (f16)t[3];
        *(f16x4*)&tiles[T1OFF + r * S1 + 4 * c4] = h;
      }
    }
  }
  {
    const float* img = x0 + nb * 4096;
    int idx = tid;
    int r  = idx / 6, c4 = idx - r * 6;
    int gy = ty * 16 - 1 + r;
    int gx = tx * 16 - 4 + 4 * c4;
    bool inb = (idx < 114) && ((unsigned)gy < 64u) && ((unsigned)gx < 64u);
    f32x4 t = inb ? *(const f32x4*)(img + gy * 64 + gx) : (f32x4){0.f, 0.f, 0.f, 0.f};
    if (idx < 114) {
      f16x4 h; h[0] = (f16)t[0]; h[1] = (f16)t[1]; h[2] = (f16)t[2]; h[3] = (f16)t[3];
      *(f16x4*)&tiles[T0OFF + r * S0 + 4 * c4] = h;
    }
  }
  __syncthreads();   // x0/x1 tiles ready (x2 loads still possibly in flight)

  f32x4 acc[4][4];
  #pragma unroll
  for (int c = 0; c < 4; ++c)
    #pragma unroll
    for (int t = 0; t < 4; ++t)
      acc[c][t] = (f32x4){0.f, 0.f, 0.f, 0.f};

  // ---- kstep 0: quads 0,1 -> layer0 ; quads 2,3 -> layer1 ----
  {
    f16x8 bf[4];
    #pragma unroll
    for (int t = 0; t < 4; ++t)
      bf[t] = *(const f16x8*)(Wt + (t * 16 + ln) * 256 + quad * 8);
    #pragma unroll
    for (int cc = 0; cc < 4; ++cc) {
      const int py = wid * 4 + cc;
      f16x8 a;
      if (quad < 2) {
        // layer0: ki = 2*quad + (j>>2), kj = j&3; row = py+ki, col = ln+3+kj
        const int a0 = T0OFF + (py + 2 * quad) * S0 + ln + 3;
        #pragma unroll
        for (int j = 0; j < 4; ++j) a[j]     = tiles[a0 + j];
        #pragma unroll
        for (int j = 0; j < 4; ++j) a[4 + j] = tiles[a0 + S0 + j];
      } else {
        // layer1: ki = quad-2, kj = j; row = 2py+ki, col = 2ln+2+kj
        const int a1 = T1OFF + (2 * py + quad - 2) * S1 + 2 * ln + 2;
        #pragma unroll
        for (int j = 0; j < 8; ++j) a[j] = tiles[a1 + j];
      }
      #pragma unroll
      for (int t = 0; t < 4; ++t)
        acc[cc][t] = __builtin_amdgcn_mfma_f32_16x16x32_f16(a, bf[t], acc[cc][t], 0, 0, 0);
    }
  }
  // ---- kstep 1: all layer1, ki = 2+quad ----
  {
    f16x8 bf[4];
    #pragma unroll
    for (int t = 0; t < 4; ++t)
      bf[t] = *(const f16x8*)(Wt + (t * 16 + ln) * 256 + 32 + quad * 8);
    #pragma unroll
    for (int cc = 0; cc < 4; ++cc) {
      const int py = wid * 4 + cc;
      const int a1 = T1OFF + (2 * py + 2 + quad) * S1 + 2 * ln + 2;
      f16x8 a;
      #pragma unroll
      for (int j = 0; j < 8; ++j) a[j] = tiles[a1 + j];
      #pragma unroll
      for (int t = 0; t < 4; ++t)
        acc[cc][t] = __builtin_amdgcn_mfma_f32_16x16x32_f16(a, bf[t], acc[cc][t], 0, 0, 0);
    }
  }

  // ---- now store x2 tile to LDS (loads have had max time to arrive) ----
  #pragma unroll
  for (int i = 0; i < 7; ++i) {
    if (ok2[i]) {
      f16x4 h0; h0[0] = (f16)v2[i][0]; h0[1] = (f16)v2[i][1];
      h0[2] = (f16)v2[i][2]; h0[3] = (f16)v2[i][3];
      *(f16x4*)&tiles[off2[i]] = h0;
    }
  }
  __syncthreads();   // x2 tile ready

  // ---- ksteps 2..7: layer2 ----
  // row = 4py + 2(s-2) + (quad>>1), col = 4ln + 4 + 8(quad&1) + j
  #pragma unroll 2
  for (int s = 2; s < 8; ++s) {
    f16x8 bf[4];
    #pragma unroll
    for (int t = 0; t < 4; ++t)
      bf[t] = *(const f16x8*)(Wt + (t * 16 + ln) * 256 + s * 32 + quad * 8);
    #pragma unroll
    for (int cc = 0; cc < 4; ++cc) {
      const int py = wid * 4 + cc;
      const int b2 = T2OFF + (4 * py + 2 * (s - 2) + (quad >> 1)) * S2 + 4 * ln + 4 + 8 * (quad & 1);
      f16x4 lo = *(const f16x4*)&tiles[b2];
      f16x4 hi = *(const f16x4*)&tiles[b2 + 4];
      f16x8 a;
      a[0] = lo[0]; a[1] = lo[1]; a[2] = lo[2]; a[3] = lo[3];
      a[4] = hi[0]; a[5] = hi[1]; a[6] = hi[2]; a[7] = hi[3];
      #pragma unroll
      for (int t = 0; t < 4; ++t)
        acc[cc][t] = __builtin_amdgcn_mfma_f32_16x16x32_f16(a, bf[t], acc[cc][t], 0, 0, 0);
    }
  }

  __syncthreads();   // all tiles reads done -> scratch may overwrite the alias

  // ---- epilogue per chunk: LDS transpose -> per-lane softmax -> coalesced stores ----
  float* swp = scratch + wid * 16 * SCRSTR;
  #pragma unroll 1
  for (int cc = 0; cc < 4; ++cc) {
    const int py = wid * 4 + cc;
    #pragma unroll
    for (int t = 0; t < 4; ++t)
      #pragma unroll
      for (int r = 0; r < 4; ++r)
        swp[(quad * 4 + r) * SCRSTR + t * 16 + ln] = fmaxf(acc[cc][t][r], 0.f);
    asm volatile("s_waitcnt lgkmcnt(0)" ::: "memory");

    f32x4 v[4];
    #pragma unroll
    for (int u = 0; u < 4; ++u)
      v[u] = *(const f32x4*)&swp[ln * SCRSTR + quad * 16 + 4 * u];
    asm volatile("s_waitcnt lgkmcnt(0)" ::: "memory");

    float m = 0.f;
    #pragma unroll
    for (int u = 0; u < 4; ++u)
      #pragma unroll
      for (int e = 0; e < 4; ++e) m = fmaxf(m, v[u][e]);
    m = fmaxf(m, __shfl_xor(m, 16));
    m = fmaxf(m, __shfl_xor(m, 32));
    float ssum = 0.f;
    #pragma unroll
    for (int u = 0; u < 4; ++u)
      #pragma unroll
      for (int e = 0; e < 4; ++e) {
        float x = exp2f((v[u][e] - m) * LOG2E);
        v[u][e] = x;
        ssum += x;
      }
    ssum += __shfl_xor(ssum, 16);
    ssum += __shfl_xor(ssum, 32);

    const int gy = ty * 16 + py;
    const int gx = tx * 16 + ln;
    const float sc = x0[nb * 4096 + gy * 64 + gx] / ssum;   // exact f32 x0

    float* op = out + nb * 262144 + (gy * 8 + 2 * quad) * 512 + gx * 8;
    *(f32x4*)(op)           = v[0] * sc;
    *(f32x4*)(op + 4)       = v[1] * sc;
    *(f32x4*)(op + 512)     = v[2] * sc;
    *(f32x4*)(op + 512 + 4) = v[3] * sc;
  }
}

extern "C" void kernel_launch(void* const* d_in, const int* in_sizes, int n_in,
                              void* d_out, int out_size, void* d_ws, size_t ws_size,
                              hipStream_t stream) {
  const float* x0 = (const float*)d_in[0];
  const float* x1 = (const float*)d_in[1];
  const float* x2 = (const float*)d_in[2];
  const float* W  = (const float*)d_in[3];
  float* outp     = (float*)d_out;
  f16* Wt         = (f16*)d_ws;   // 64*256 f16 = 32 KB

  prep_wt<<<dim3(64), dim3(256), 0, stream>>>(W, Wt);
  fuse_kernel<<<dim3(1024), dim3(256), 0, stream>>>(x0, x1, x2, Wt, outp);
}

// Round 6
// 117.239 us; speedup vs baseline: 1.4528x; 1.4528x over previous
//
#include <hip/hip_runtime.h>

typedef _Float16 f16;
typedef f16 f16x8 __attribute__((ext_vector_type(8)));
typedef f16 f16x4 __attribute__((ext_vector_type(4)));
typedef float f32x4 __attribute__((ext_vector_type(4)));

// ---- LDS tile strides/offsets (units: f16 elements) ----
// x0: 19 rows x 24 cols (gx in [tx*16-4,  tx*16+20)), stride 28
// x1: 36 rows x 44 cols (gx in [tx*32-4,  tx*32+40)), stride 48
// x2: 76 rows x 88 cols (gx in [tx*64-8,  tx*64+80)), stride 92
#define S0 28
#define S1 48
#define S2 92
#define T0OFF 0
#define T1OFF (19 * S0)                 // 532
#define T2OFF (T1OFF + 36 * S1)         // 2260
#define TILEH (T2OFF + 76 * S2)         // 9252 f16 = 18504 B
#define SCRSTR 68                       // scratch row stride (floats)
#define SMEM_BYTES 34816                // max(tiles 18504, scratch 2*4*16*68*4 = 34816)
#define LOG2E 1.4426950408889634f

// K' = 256 layout (8 ksteps of 32):
//  kp in [0,16)   : layer0, ki=kp>>2, kj=kp&3   ; real iff ki<3 && kj<3 -> orig = 3*ki+kj
//  kp in [16,64)  : layer1, kk=kp-16, ki=kk>>3, kj=kk&7 ; real iff kj<6 -> orig = 9+6*ki+kj
//  kp in [64,256) : layer2, kk=kp-64, ki=kk>>4, kj=kk&15; real iff kj<12 -> orig = 45+12*ki+kj
//
// Fragment-major storage: fragment f = (s*4 + t)*64 + lane holds the 8 f16
// B-elements (k = s*32 + quad*8 + j, n = t*16 + ln) -> every wave bf load is
// 64 lanes x 16 B CONTIGUOUS (1 KB), address = lane*16B + uniform offset.
__global__ void prep_wt(const float* __restrict__ W, f16* __restrict__ Wt) {
  const int f = blockIdx.x * 256 + threadIdx.x;   // 0..2047
  const int s = f >> 8;
  const int t = (f >> 6) & 3;
  const int lane = f & 63;
  const int quad = lane >> 4, ln = lane & 15;
  const int n = t * 16 + ln;
  f16 vals[8];
  #pragma unroll
  for (int j = 0; j < 8; ++j) {
    int kp = s * 32 + quad * 8 + j;
    int orig = -1;
    if (kp < 16)      { int ki = kp >> 2, kj = kp & 3;                   if (ki < 3 && kj < 3) orig = 3*ki + kj; }
    else if (kp < 64) { int kk = kp - 16; int ki = kk >> 3, kj = kk & 7;  if (kj < 6)          orig = 9 + 6*ki + kj; }
    else              { int kk = kp - 64; int ki = kk >> 4, kj = kk & 15; if (kj < 12)         orig = 45 + 12*ki + kj; }
    vals[j] = (f16)((orig >= 0) ? W[orig * 64 + n] : 0.f);
  }
  *(f16x8*)(Wt + (size_t)f * 8) = *(const f16x8*)vals;
}

__global__ __launch_bounds__(256, 3) void fuse_kernel(
    const float* __restrict__ x0, const float* __restrict__ x1,
    const float* __restrict__ x2, const f16* __restrict__ Wt,
    float* __restrict__ out)
{
  // scratch aliases tiles: tiles used staging+K-loop, scratch used in epilogue
  // (separated by a __syncthreads after the K-loop).
  __shared__ __align__(16) char smem_raw[SMEM_BYTES];
  f16*   tiles   = (f16*)smem_raw;
  float* scratch = (float*)smem_raw;

  const int tid  = threadIdx.x;
  const int bid  = blockIdx.x;
  const int nb   = bid >> 4;          // image
  const int ty   = (bid >> 2) & 3;    // 16-px tile row
  const int tx   = bid & 3;           // 16-px tile col
  const int lane = tid & 63;
  const int wid  = tid >> 6;
  const int ln   = lane & 15;
  const int quad = lane >> 4;

  // per-lane base for fragment-major Wt
  const f16* __restrict__ wfrag = Wt + (size_t)lane * 8;

  // ================= issue x2 loads FIRST (biggest input, longest latency) ==
  // 76 rows x 22 float4 = 1672 items
  f32x4 v2[7];
  int   off2[7];
  bool  ok2[7];
  {
    const float* img = x2 + nb * 65536;
    #pragma unroll
    for (int i = 0; i < 7; ++i) {
      int idx = tid + 256 * i;
      int r  = idx / 22, c4 = idx - r * 22;
      int gy = ty * 64 - 4 + r;
      int gx = tx * 64 - 8 + 4 * c4;
      bool inb = (idx < 1672) && ((unsigned)gy < 256u) && ((unsigned)gx < 256u);
      v2[i]  = inb ? *(const f32x4*)(img + gy * 256 + gx) : (f32x4){0.f, 0.f, 0.f, 0.f};
      off2[i] = T2OFF + r * S2 + 4 * c4;
      ok2[i]  = (idx < 1672);
    }
  }

  // ================= stage x1 (36 x 11 float4 = 396) and x0 (19 x 6 = 114) ==
  {
    const float* img = x1 + nb * 16384;
    #pragma unroll
    for (int i = 0; i < 2; ++i) {
      int idx = tid + 256 * i;
      int r  = idx / 11, c4 = idx - r * 11;
      int gy = ty * 32 - 2 + r;
      int gx = tx * 32 - 4 + 4 * c4;
      bool inb = (idx < 396) && ((unsigned)gy < 128u) && ((unsigned)gx < 128u);
      f32x4 t = inb ? *(const f32x4*)(img + gy * 128 + gx) : (f32x4){0.f, 0.f, 0.f, 0.f};
      if (idx < 396) {
        f16x4 h; h[0] = (f16)t[0]; h[1] = (f16)t[1]; h[2] = (f16)t[2]; h[3] = (f16)t[3];
        *(f16x4*)&tiles[T1OFF + r * S1 + 4 * c4] = h;
      }
    }
  }
  {
    const float* img = x0 + nb * 4096;
    int idx = tid;
    int r  = idx / 6, c4 = idx - r * 6;
    int gy = ty * 16 - 1 + r;
    int gx = tx * 16 - 4 + 4 * c4;
    bool inb = (idx < 114) && ((unsigned)gy < 64u) && ((unsigned)gx < 64u);
    f32x4 t = inb ? *(const f32x4*)(img + gy * 64 + gx) : (f32x4){0.f, 0.f, 0.f, 0.f};
    if (idx < 114) {
      f16x4 h; h[0] = (f16)t[0]; h[1] = (f16)t[1]; h[2] = (f16)t[2]; h[3] = (f16)t[3];
      *(f16x4*)&tiles[T0OFF + r * S0 + 4 * c4] = h;
    }
  }

  // x0 scale pixels for the epilogue (exact f32), issued early so the
  // latency is hidden under the K-loop. Lane needs pixel (ty*16+wid*4+cc, tx*16+ln).
  float xs[4];
  #pragma unroll
  for (int cc = 0; cc < 4; ++cc)
    xs[cc] = x0[nb * 4096 + (ty * 16 + wid * 4 + cc) * 64 + tx * 16 + ln];

  __syncthreads();   // x0/x1 tiles ready (x2 loads still possibly in flight)

  f32x4 acc[4][4];
  #pragma unroll
  for (int c = 0; c < 4; ++c)
    #pragma unroll
    for (int t = 0; t < 4; ++t)
      acc[c][t] = (f32x4){0.f, 0.f, 0.f, 0.f};

  // ---- kstep 0: quads 0,1 -> layer0 ; quads 2,3 -> layer1 ----
  {
    f16x8 bf[4];
    #pragma unroll
    for (int t = 0; t < 4; ++t)
      bf[t] = *(const f16x8*)(wfrag + t * 512);
    #pragma unroll
    for (int cc = 0; cc < 4; ++cc) {
      const int py = wid * 4 + cc;
      f16x8 a;
      if (quad < 2) {
        // layer0: ki = 2*quad + (j>>2), kj = j&3; row = py+ki, col = ln+3+kj
        const int a0 = T0OFF + (py + 2 * quad) * S0 + ln + 3;
        #pragma unroll
        for (int j = 0; j < 4; ++j) a[j]     = tiles[a0 + j];
        #pragma unroll
        for (int j = 0; j < 4; ++j) a[4 + j] = tiles[a0 + S0 + j];
      } else {
        // layer1: ki = quad-2, kj = j; row = 2py+ki, col = 2ln+2+kj
        const int a1 = T1OFF + (2 * py + quad - 2) * S1 + 2 * ln + 2;
        #pragma unroll
        for (int j = 0; j < 8; ++j) a[j] = tiles[a1 + j];
      }
      #pragma unroll
      for (int t = 0; t < 4; ++t)
        acc[cc][t] = __builtin_amdgcn_mfma_f32_16x16x32_f16(a, bf[t], acc[cc][t], 0, 0, 0);
    }
  }
  // ---- kstep 1: all layer1, ki = 2+quad ----
  {
    f16x8 bf[4];
    #pragma unroll
    for (int t = 0; t < 4; ++t)
      bf[t] = *(const f16x8*)(wfrag + (4 + t) * 512);
    #pragma unroll
    for (int cc = 0; cc < 4; ++cc) {
      const int py = wid * 4 + cc;
      const int a1 = T1OFF + (2 * py + 2 + quad) * S1 + 2 * ln + 2;
      f16x8 a;
      #pragma unroll
      for (int j = 0; j < 8; ++j) a[j] = tiles[a1 + j];
      #pragma unroll
      for (int t = 0; t < 4; ++t)
        acc[cc][t] = __builtin_amdgcn_mfma_f32_16x16x32_f16(a, bf[t], acc[cc][t], 0, 0, 0);
    }
  }

  // ---- now store x2 tile to LDS (loads have had max time to arrive) ----
  #pragma unroll
  for (int i = 0; i < 7; ++i) {
    if (ok2[i]) {
      f16x4 h0; h0[0] = (f16)v2[i][0]; h0[1] = (f16)v2[i][1];
      h0[2] = (f16)v2[i][2]; h0[3] = (f16)v2[i][3];
      *(f16x4*)&tiles[off2[i]] = h0;
    }
  }
  __syncthreads();   // x2 tile ready

  // ---- ksteps 2..7: layer2 ----
  // row = 4py + 2(s-2) + (quad>>1), col = 4ln + 4 + 8(quad&1) + j
  #pragma unroll 3
  for (int s = 2; s < 8; ++s) {
    f16x8 bf[4];
    #pragma unroll
    for (int t = 0; t < 4; ++t)
      bf[t] = *(const f16x8*)(wfrag + (s * 4 + t) * 512);
    #pragma unroll
    for (int cc = 0; cc < 4; ++cc) {
      const int py = wid * 4 + cc;
      const int b2 = T2OFF + (4 * py + 2 * (s - 2) + (quad >> 1)) * S2 + 4 * ln + 4 + 8 * (quad & 1);
      f16x4 lo = *(const f16x4*)&tiles[b2];
      f16x4 hi = *(const f16x4*)&tiles[b2 + 4];
      f16x8 a;
      a[0] = lo[0]; a[1] = lo[1]; a[2] = lo[2]; a[3] = lo[3];
      a[4] = hi[0]; a[5] = hi[1]; a[6] = hi[2]; a[7] = hi[3];
      #pragma unroll
      for (int t = 0; t < 4; ++t)
        acc[cc][t] = __builtin_amdgcn_mfma_f32_16x16x32_f16(a, bf[t], acc[cc][t], 0, 0, 0);
    }
  }

  __syncthreads();   // all tiles reads done -> scratch may overwrite the alias

  // ---- epilogue, pair-wise: transpose 2 chunks -> 1 wait -> 2 softmax chains ----
  float* swp0 = scratch + wid * 16 * SCRSTR;        // buffer A (this wave)
  float* swp1 = scratch + (4 + wid) * 16 * SCRSTR;  // buffer B (this wave)
  #pragma unroll
  for (int cp = 0; cp < 2; ++cp) {
    const int c0 = 2 * cp, c1 = 2 * cp + 1;
    #pragma unroll
    for (int t = 0; t < 4; ++t)
      #pragma unroll
      for (int r = 0; r < 4; ++r) {
        swp0[(quad * 4 + r) * SCRSTR + t * 16 + ln] = fmaxf(acc[c0][t][r], 0.f);
        swp1[(quad * 4 + r) * SCRSTR + t * 16 + ln] = fmaxf(acc[c1][t][r], 0.f);
      }
    asm volatile("s_waitcnt lgkmcnt(0)" ::: "memory");

    f32x4 v0[4], v1[4];
    #pragma unroll
    for (int u = 0; u < 4; ++u) {
      v0[u] = *(const f32x4*)&swp0[ln * SCRSTR + quad * 16 + 4 * u];
      v1[u] = *(const f32x4*)&swp1[ln * SCRSTR + quad * 16 + 4 * u];
    }

    float m0 = 0.f, m1 = 0.f;
    #pragma unroll
    for (int u = 0; u < 4; ++u)
      #pragma unroll
      for (int e = 0; e < 4; ++e) {
        m0 = fmaxf(m0, v0[u][e]);
        m1 = fmaxf(m1, v1[u][e]);
      }
    m0 = fmaxf(m0, __shfl_xor(m0, 16));
    m1 = fmaxf(m1, __shfl_xor(m1, 16));
    m0 = fmaxf(m0, __shfl_xor(m0, 32));
    m1 = fmaxf(m1, __shfl_xor(m1, 32));

    float s0 = 0.f, s1 = 0.f;
    #pragma unroll
    for (int u = 0; u < 4; ++u)
      #pragma unroll
      for (int e = 0; e < 4; ++e) {
        float e0 = exp2f((v0[u][e] - m0) * LOG2E);
        float e1 = exp2f((v1[u][e] - m1) * LOG2E);
        v0[u][e] = e0; v1[u][e] = e1;
        s0 += e0; s1 += e1;
      }
    s0 += __shfl_xor(s0, 16);
    s1 += __shfl_xor(s1, 16);
    s0 += __shfl_xor(s0, 32);
    s1 += __shfl_xor(s1, 32);

    const float sc0 = xs[c0] / s0;
    const float sc1 = xs[c1] / s1;

    const int gx = tx * 16 + ln;
    {
      const int gy = ty * 16 + wid * 4 + c0;
      float* op = out + nb * 262144 + (gy * 8 + 2 * quad) * 512 + gx * 8;
      *(f32x4*)(op)           = v0[0] * sc0;
      *(f32x4*)(op + 4)       = v0[1] * sc0;
      *(f32x4*)(op + 512)     = v0[2] * sc0;
      *(f32x4*)(op + 512 + 4) = v0[3] * sc0;
    }
    {
      const int gy = ty * 16 + wid * 4 + c1;
      float* op = out + nb * 262144 + (gy * 8 + 2 * quad) * 512 + gx * 8;
      *(f32x4*)(op)           = v1[0] * sc1;
      *(f32x4*)(op + 4)       = v1[1] * sc1;
      *(f32x4*)(op + 512)     = v1[2] * sc1;
      *(f32x4*)(op + 512 + 4) = v1[3] * sc1;
    }
    // buffers reused next pair only after these reads complete (program order
    // of DS ops within a wave + lgkmcnt wait at top of next iteration).
  }
}

extern "C" void kernel_launch(void* const* d_in, const int* in_sizes, int n_in,
                              void* d_out, int out_size, void* d_ws, size_t ws_size,
                              hipStream_t stream) {
  const float* x0 = (const float*)d_in[0];
  const float* x1 = (const float*)d_in[1];
  const float* x2 = (const float*)d_in[2];
  const float* W  = (const float*)d_in[3];
  float* outp     = (float*)d_out;
  f16* Wt         = (f16*)d_ws;   // 2048 fragments * 16 B = 32 KB

  prep_wt<<<dim3(8), dim3(256), 0, stream>>>(W, Wt);
  fuse_kernel<<<dim3(1024), dim3(256), 0, stream>>>(x0, x1, x2, Wt, outp);
}